// Round 5
// baseline (184.521 us; speedup 1.0000x reference)
//
#include <hip/hip_runtime.h>

typedef unsigned short u16;
typedef unsigned int   u32;
typedef __attribute__((ext_vector_type(8))) short bf16x8;  // 8 bf16 (4 VGPRs)
typedef __attribute__((ext_vector_type(4))) float f32x4;   // MFMA acc

#define NEL (8192*128)

// async global->LDS, 16B per lane, LDS dest = wave-uniform base + lane*16
#define ASYNC16(ldsptr, gptr) __builtin_amdgcn_global_load_lds( \
    (const __attribute__((address_space(1))) u32*)(gptr), \
    (__attribute__((address_space(3))) u32*)(ldsptr), 16, 0, 0)

__device__ __forceinline__ u16 f2bf(float f){
  u32 u = __builtin_bit_cast(u32, f);
  u = (u + 0x7FFFu + ((u >> 16) & 1u)) >> 16;  // RNE
  return (u16)u;
}
__device__ __forceinline__ u32 pk2(float a, float b){  // lo=bf16(a), hi=bf16(b)
  u32 r;
  asm("v_cvt_pk_bf16_f32 %0, %1, %2" : "=v"(r) : "v"(a), "v"(b));
  return r;
}

// ---------------- prep ----------------
// blocks 0..63: LDS histogram of degrees -> partial[b][8192] (NO global atomics)
// blocks 64..159: weight bf16 transpose WT[6][128][128], WT[w][n][k] = W_w[k][n]
__global__ __launch_bounds__(256) void prep_kernel(
    const int* __restrict__ eab, const int* __restrict__ eba, float* __restrict__ partial,
    const float* __restrict__ Wq, const float* __restrict__ Wk, const float* __restrict__ Wv,
    const float* __restrict__ Wo, const float* __restrict__ W1, const float* __restrict__ W2,
    u16* __restrict__ WT)
{
  __shared__ u32 hist[8192];
  __shared__ float tile[32][33];
  const int b = blockIdx.x, t = threadIdx.x;
  if (b < 64){
    #pragma unroll
    for (int i=0;i<32;i++) hist[t + i*256] = 0u;
    __syncthreads();
    const int e0 = b*1024;
    #pragma unroll
    for (int i=0;i<4;i++){
      int e = e0 + t + i*256;
      atomicAdd(&hist[eab[e]],              1u);  // edge_ab src -> deg_a
      atomicAdd(&hist[4096 + eab[65536+e]], 1u);  // edge_ab dst -> deg_b
      atomicAdd(&hist[4096 + eba[e]],       1u);  // edge_ba src -> deg_b
      atomicAdd(&hist[eba[65536+e]],        1u);  // edge_ba dst -> deg_a
    }
    __syncthreads();
    #pragma unroll
    for (int i=0;i<32;i++){
      int bin = t + i*256;
      partial[b*8192 + bin] = (float)hist[bin];
    }
  } else {
    int id = b - 64;                  // 0..95 = 6 W x 16 tiles(32x32)
    int w = id >> 4, tt = id & 15, tr = tt >> 2, tc = tt & 3;
    const float* W = (w==0)?Wq:(w==1)?Wk:(w==2)?Wv:(w==3)?Wo:(w==4)?W1:W2;
    int r = t >> 3, c4 = (t&7)*4;
    float4 v = *(const float4*)(W + (tr*32 + r)*128 + tc*32 + c4);
    tile[r][c4]=v.x; tile[r][c4+1]=v.y; tile[r][c4+2]=v.z; tile[r][c4+3]=v.w;
    __syncthreads();
    int n = t >> 3, k4 = (t&7)*4;     // write WT[w][tc*32+n][tr*32+k4..+3]
    u32 lo = pk2(tile[k4+0][n], tile[k4+1][n]);
    u32 hi = pk2(tile[k4+2][n], tile[k4+3][n]);
    *(uint2*)(WT + w*16384 + (tc*32+n)*128 + tr*32 + k4) = make_uint2(lo, hi);
  }
}

// ---------------- LN(x); MFMA x@{Wq,Wk,Wv}+b -> bf16 Q(pre-scaled),K,V^T ----------------
// 512 blocks x 512 thr (8 waves), 16 rows/block; wave w -> cols 16w..16w+15
// blocks 0..31 additionally reduce partial[64][8192] -> deg[8192] (coalesced)
__global__ __launch_bounds__(512) void ln_qkv_kernel(
    const float* __restrict__ xa, const float* __restrict__ xb,
    const float* __restrict__ g, const float* __restrict__ bvec,
    const u16* __restrict__ WT,
    const float* __restrict__ bq, const float* __restrict__ bk, const float* __restrict__ bv,
    const float* __restrict__ partial, float* __restrict__ deg,
    u16* __restrict__ Qb, u16* __restrict__ Kb, u16* __restrict__ VT)
{
  __shared__ float xs[16][132];
  __shared__ __align__(16) u16 abf[16][128];   // bf16 A-tile, 16B chunks XOR-swizzled
  __shared__ __align__(16) u16 vtb[128][24];   // V^T bounce (stride 48B)
  const int t = threadIdx.x, lane = t&63, wave = t>>6;
  const int lq = lane&15, lg = lane>>4;
  const int row0 = blockIdx.x*16;
  const float* x = (row0 < 4096) ? (xa + row0*128) : (xb + (row0-4096)*128);
  { // stage 16x128 f32: one float4/thread
    int r = t>>5, c4 = (t&31)*4;
    float4 v = *(const float4*)(x + r*128 + c4);
    xs[r][c4]=v.x; xs[r][c4+1]=v.y; xs[r][c4+2]=v.z; xs[r][c4+3]=v.w;
  }
  __syncthreads();
  if (t < 256){ // LN, 16 threads/row; write bf16 swizzled A-tile
    int r = t>>4, c0 = t&15;
    float s=0.f, s2=0.f;
    #pragma unroll
    for (int j=0;j<8;j++){ float v = xs[r][c0+j*16]; s+=v; s2+=v*v; }
    #pragma unroll
    for (int m=1;m<16;m<<=1){ s += __shfl_xor(s,m); s2 += __shfl_xor(s2,m); }
    float mean = s*0.0078125f;
    float var  = s2*0.0078125f - mean*mean;
    float rstd = rsqrtf(var + 1e-5f);
    #pragma unroll
    for (int j=0;j<8;j++){
      int c = c0 + j*16;
      float h = (xs[r][c]-mean)*rstd*g[c] + bvec[c];
      int sj = (c>>3) ^ (r&7);
      abf[r][sj*8 + (c&7)] = f2bf(h);
    }
  }
  __syncthreads();
  // A-frags: row=lq, k=s*32+lg*8
  bf16x8 af[4];
  #pragma unroll
  for (int s=0;s<4;s++){
    int sj = (s*4+lg) ^ (lq&7);
    af[s] = *(const bf16x8*)&abf[lq][sj*8];
  }
  const int cb = wave*16;
  const float QSC = 0.17677669529663687f * 1.4426950408889634f; // 1/sqrt(32)*log2e
  #pragma unroll
  for (int m=0;m<3;m++){
    const u16* Wg = WT + m*16384;
    bf16x8 bfr[4];
    #pragma unroll
    for (int s=0;s<4;s++)
      bfr[s] = *(const bf16x8*)(Wg + (cb+lq)*128 + s*32 + lg*8);
    f32x4 acc = {0,0,0,0};
    #pragma unroll
    for (int s=0;s<4;s++)
      acc = __builtin_amdgcn_mfma_f32_16x16x32_bf16(af[s], bfr[s], acc, 0,0,0);
    int col = cb + lq;
    if (m==0){
      float bb = bq[col];
      #pragma unroll
      for (int r=0;r<4;r++)
        Qb[(row0+4*lg+r)*128 + col] = f2bf((acc[r]+bb)*QSC);
    } else if (m==1){
      float bb = bk[col];
      #pragma unroll
      for (int r=0;r<4;r++)
        Kb[(row0+4*lg+r)*128 + col] = f2bf(acc[r]+bb);
    } else {
      float bb = bv[col];
      #pragma unroll
      for (int r=0;r<4;r++)
        vtb[col][4*lg+r] = f2bf(acc[r]+bb);
    }
  }
  __syncthreads();
  if (t < 256){ // V^T global write: c = t>>1, half = t&1 (16B each)
    int c = t>>1, half = t&1;
    bf16x8 v = *(const bf16x8*)&vtb[c][half*8];
    *(bf16x8*)(VT + c*8192 + row0 + half*8) = v;
  }
  if (blockIdx.x < 32 && t < 256){ // deg reduce: 32 blocks x 256 bins
    int bin = blockIdx.x*256 + t;
    float s = 0.f;
    #pragma unroll
    for (int j=0;j<64;j++) s += partial[j*8192 + bin];
    deg[bin] = s;
  }
}

// ---------------- flash attention: per-head, KV-split x4, m==0 softmax ----------------
// grid (64, 4 heads, 8 = dir*4+split); block 256 = 4 waves x 16 q; KBLK=64, 16 tiles.
__global__ __launch_bounds__(256) void attn_kernel(
    const u16* __restrict__ Qb, const u16* __restrict__ Kb,
    const u16* __restrict__ VT, float* __restrict__ numb, float* __restrict__ denb)
{
  __shared__ __align__(16) u16 Klds[2][2048];   // 64 keys x 4 chunks
  __shared__ __align__(16) u16 Vlds[2][2048];   // 32 d x 8 chunks
  __shared__ __align__(16) u16 Plds[4][1024];   // per wave: 16 q x 8 chunks
  const int t = threadIdx.x, wave = t>>6, lane = t&63;
  const int lq = lane&15, lg = lane>>4;
  const int h = blockIdx.y;
  const int dir = blockIdx.z >> 2, sp = blockIdx.z & 3;
  const int q = blockIdx.x*64 + wave*16 + lq + (dir ? 4096 : 0);
  const int kvb = (dir ? 0 : 4096) + sp*1024;

  bf16x8 qf = *(const bf16x8*)(Qb + q*128 + h*32 + lg*8);
  f32x4 acc0 = {0,0,0,0}, acc1 = {0,0,0,0}, accL = {0,0,0,0};
  bf16x8 ones;
  #pragma unroll
  for (int i=0;i<8;i++) ones[i] = (short)0x3F80;

  // staging sources: K thread t -> key=t>>2, chunk j=t&3, src cc = j ^ ((key>>1)&3)
  //                  V thread t -> d=t>>3, chunk j=t&7,  src cc = j ^ (d&7)
  const u16* gk = Kb + (kvb + (t>>2))*128 + h*32 + ((t&3) ^ ((t>>3)&3))*8;
  const u16* gv = VT + (h*32 + (t>>3))*8192 + kvb + ((t&7) ^ ((t>>3)&7))*8;

  ASYNC16(&Klds[0][t*8], gk);
  ASYNC16(&Vlds[0][t*8], gv);
  asm volatile("s_waitcnt vmcnt(0)" ::: "memory");
  __builtin_amdgcn_s_barrier();

  int cur = 0;
  for (int kt=0; kt<16; ++kt){
    if (kt < 15){
      gk += 8192; gv += 64;
      ASYNC16(&Klds[cur^1][t*8], gk);
      ASYNC16(&Vlds[cur^1][t*8], gv);
    }
    const u16* KL = Klds[cur];
    const u16* VL = Vlds[cur];
    u16* PL = Plds[wave] + lq*64;
    // S^T (4 MFMA) -> exp2 -> pack -> P LDS
    const int ksj = lg ^ ((lq>>1)&3);
    #pragma unroll
    for (int f=0; f<4; ++f){
      bf16x8 kf = *(const bf16x8*)(KL + (f*16+lq)*32 + ksj*8);
      f32x4 st = __builtin_amdgcn_mfma_f32_16x16x32_bf16(kf, qf, (f32x4){0.f,0.f,0.f,0.f}, 0,0,0);
      float p0 = __builtin_amdgcn_exp2f(st[0]);
      float p1 = __builtin_amdgcn_exp2f(st[1]);
      float p2 = __builtin_amdgcn_exp2f(st[2]);
      float p3 = __builtin_amdgcn_exp2f(st[3]);
      int j = f*2 + (lg>>1);
      *(uint2*)(PL + ((j ^ (lq&7))<<3) + (lg&1)*4) = make_uint2(pk2(p0,p1), pk2(p2,p3));
    }
    // PV + l-sum: 6 MFMA
    #pragma unroll
    for (int kc=0; kc<2; ++kc){
      int sj = (kc*4+lg) ^ (lq&7);
      bf16x8 pf  = *(const bf16x8*)(PL + (sj<<3));
      bf16x8 vf0 = *(const bf16x8*)(VL + lq*64      + (sj<<3));
      bf16x8 vf1 = *(const bf16x8*)(VL + (16+lq)*64 + (sj<<3));
      acc0 = __builtin_amdgcn_mfma_f32_16x16x32_bf16(vf0,  pf, acc0, 0,0,0);
      acc1 = __builtin_amdgcn_mfma_f32_16x16x32_bf16(vf1,  pf, acc1, 0,0,0);
      accL = __builtin_amdgcn_mfma_f32_16x16x32_bf16(ones, pf, accL, 0,0,0);
    }
    asm volatile("s_waitcnt vmcnt(0)" ::: "memory");
    __builtin_amdgcn_s_barrier();
    cur ^= 1;
  }
  float* outp = numb + sp*NEL + q*128 + h*32 + 4*lg;   // d = h*32 + 4lg + r
  *(float4*)(outp)      = make_float4(acc0[0], acc0[1], acc0[2], acc0[3]);
  *(float4*)(outp + 16) = make_float4(acc1[0], acc1[1], acc1[2], acc1[3]);
  if (lg == 0) denb[sp*32768 + q*4 + h] = accL[0];
}

// ---------------- MFMA tail: combine splits; @Wo+bo+deg+x -> res ; LN;LN ; @W1+gelu ; @W2+b2+res ----------------
// 512 blocks x 512 thr (8 waves), 16 rows; wave w -> cols 16w..+15
__global__ __launch_bounds__(512) void tail_kernel(
    const float* __restrict__ numb, const float* __restrict__ denb,
    const u16* __restrict__ WT,
    const float* __restrict__ bo, const float* __restrict__ deg,
    const float* __restrict__ xa, const float* __restrict__ xb,
    const float* __restrict__ gf1, const float* __restrict__ bf1,
    const float* __restrict__ gf2, const float* __restrict__ bf2,
    const float* __restrict__ b1, const float* __restrict__ b2,
    float* __restrict__ out)
{
  __shared__ __align__(16) u16 abf[16][128];
  __shared__ float rs[16][132];
  const int t = threadIdx.x, lane = t&63, wave = t>>6;
  const int lq = lane&15, lg = lane>>4;
  const int row0 = blockIdx.x*16;
  const int cb = wave*16;

  { // combine 4 KV-split partials, normalize, -> bf16 swizzled A-tile
    int r = t>>5, c0 = (t&31)*4, hh = c0>>5;
    const float* np = numb + (row0+r)*128 + c0;
    float4 s0 = *(const float4*)(np);
    float4 s1 = *(const float4*)(np + NEL);
    float4 s2 = *(const float4*)(np + 2*NEL);
    float4 s3 = *(const float4*)(np + 3*NEL);
    int di = (row0+r)*4 + hh;
    float den = denb[di] + denb[32768+di] + denb[65536+di] + denb[98304+di];
    float inv = 1.0f/den;
    float a0 = (s0.x+s1.x+s2.x+s3.x)*inv;
    float a1 = (s0.y+s1.y+s2.y+s3.y)*inv;
    float a2 = (s0.z+s1.z+s2.z+s3.z)*inv;
    float a3 = (s0.w+s1.w+s2.w+s3.w)*inv;
    int sj = (c0>>3) ^ (r&7);
    *(uint2*)&abf[r][sj*8 + (c0&7)] = make_uint2(pk2(a0,a1), pk2(a2,a3));
  }
  __syncthreads();

  bf16x8 af[4];
  #pragma unroll
  for (int s=0;s<4;s++){ int sj = (s*4+lg) ^ (lq&7); af[s] = *(const bf16x8*)&abf[lq][sj*8]; }

  // GEMM1: @Wo
  f32x4 acc = {0,0,0,0};
  {
    const u16* Wg = WT + 3*16384;
    bf16x8 bfr[4];
    #pragma unroll
    for (int s=0;s<4;s++) bfr[s] = *(const bf16x8*)(Wg + (cb+lq)*128 + s*32 + lg*8);
    #pragma unroll
    for (int s=0;s<4;s++) acc = __builtin_amdgcn_mfma_f32_16x16x32_bf16(af[s], bfr[s], acc, 0,0,0);
  }
  // epilogue1: res = c + bo + deg + x
  const float* xres = (row0<4096)? (xa + row0*128) : (xb + (row0-4096)*128);
  const int col = cb + lq;
  float rv[4];
  {
    float bb = bo[col];
    #pragma unroll
    for (int r=0;r<4;r++){
      int lr = 4*lg + r;
      rv[r] = acc[r] + bb + deg[row0+lr] + xres[lr*128 + col];
      rs[lr][col] = rv[r];
    }
  }
  __syncthreads();
  if (t < 256){ // LN(gf1) then LN(gf2); write bf16 swizzled into abf
    int r = t>>4, c0 = t&15;
    float s=0.f, s2=0.f;
    #pragma unroll
    for (int j=0;j<8;j++){ float v = rs[r][c0+j*16]; s+=v; s2+=v*v; }
    #pragma unroll
    for (int m=1;m<16;m<<=1){ s += __shfl_xor(s,m); s2 += __shfl_xor(s2,m); }
    float mean = s*0.0078125f;
    float var  = s2*0.0078125f - mean*mean;
    float rstd = rsqrtf(var + 1e-5f);
    float h8[8];
    #pragma unroll
    for (int j=0;j<8;j++){ int c=c0+j*16; h8[j] = (rs[r][c]-mean)*rstd*gf1[c] + bf1[c]; }
    s=0.f; s2=0.f;
    #pragma unroll
    for (int j=0;j<8;j++){ s+=h8[j]; s2+=h8[j]*h8[j]; }
    #pragma unroll
    for (int m=1;m<16;m<<=1){ s += __shfl_xor(s,m); s2 += __shfl_xor(s2,m); }
    float mean2 = s*0.0078125f;
    float var2  = s2*0.0078125f - mean2*mean2;
    float rstd2 = rsqrtf(var2 + 1e-5f);
    #pragma unroll
    for (int j=0;j<8;j++){
      int c = c0 + j*16;
      float h = (h8[j]-mean2)*rstd2*gf2[c] + bf2[c];
      int sj = (c>>3) ^ (r&7);
      abf[r][sj*8 + (c&7)] = f2bf(h);
    }
  }
  __syncthreads();
  // GEMM2: @W1 -> gelu
  #pragma unroll
  for (int s=0;s<4;s++){ int sj = (s*4+lg) ^ (lq&7); af[s] = *(const bf16x8*)&abf[lq][sj*8]; }
  acc = (f32x4){0,0,0,0};
  {
    const u16* Wg = WT + 4*16384;
    bf16x8 bfr[4];
    #pragma unroll
    for (int s=0;s<4;s++) bfr[s] = *(const bf16x8*)(Wg + (cb+lq)*128 + s*32 + lg*8);
    #pragma unroll
    for (int s=0;s<4;s++) acc = __builtin_amdgcn_mfma_f32_16x16x32_bf16(af[s], bfr[s], acc, 0,0,0);
  }
  float gvv[4];
  {
    float bb = b1[col];
    #pragma unroll
    for (int r=0;r<4;r++){
      float v = acc[r] + bb;
      gvv[r] = 0.5f*v*(1.f + erff(v*0.70710678118654752f));
    }
  }
  __syncthreads();   // all GEMM2 A-reads done before overwrite
  #pragma unroll
  for (int r=0;r<4;r++){
    int lr = 4*lg + r;
    int sj = (col>>3) ^ (lr&7);
    abf[lr][sj*8 + (col&7)] = f2bf(gvv[r]);
  }
  __syncthreads();
  // GEMM3: @W2 + b2 + res -> out
  #pragma unroll
  for (int s=0;s<4;s++){ int sj = (s*4+lg) ^ (lq&7); af[s] = *(const bf16x8*)&abf[lq][sj*8]; }
  acc = (f32x4){0,0,0,0};
  {
    const u16* Wg = WT + 5*16384;
    bf16x8 bfr[4];
    #pragma unroll
    for (int s=0;s<4;s++) bfr[s] = *(const bf16x8*)(Wg + (cb+lq)*128 + s*32 + lg*8);
    #pragma unroll
    for (int s=0;s<4;s++) acc = __builtin_amdgcn_mfma_f32_16x16x32_bf16(af[s], bfr[s], acc, 0,0,0);
  }
  {
    float bb = b2[col];
    #pragma unroll
    for (int r=0;r<4;r++){
      int lr = 4*lg + r;
      out[(row0+lr)*128 + col] = acc[r] + bb + rv[r];
    }
  }
}

extern "C" void kernel_launch(void* const* d_in, const int* in_sizes, int n_in,
                              void* d_out, int out_size, void* d_ws, size_t ws_size,
                              hipStream_t stream) {
  const float* xa  = (const float*)d_in[0];
  const float* xb  = (const float*)d_in[1];
  const int*   eab = (const int*)d_in[2];
  const int*   eba = (const int*)d_in[3];
  const float* Wq  = (const float*)d_in[4];   const float* bq = (const float*)d_in[5];
  const float* Wk  = (const float*)d_in[6];   const float* bk = (const float*)d_in[7];
  const float* Wv  = (const float*)d_in[8];   const float* bv = (const float*)d_in[9];
  const float* Wo  = (const float*)d_in[10];  const float* bo = (const float*)d_in[11];
  const float* ga  = (const float*)d_in[12];  const float* ba = (const float*)d_in[13];
  const float* gfn = (const float*)d_in[14];  const float* bfn= (const float*)d_in[15];
  const float* gf  = (const float*)d_in[16];  const float* bf = (const float*)d_in[17];
  const float* W1  = (const float*)d_in[18];  const float* b1 = (const float*)d_in[19];
  const float* W2  = (const float*)d_in[20];  const float* b2 = (const float*)d_in[21];
  float* out = (float*)d_out;

  // ws: deg 32KB | WT 192KB | Qb,Kb,VT 2MB each | numb 16MB | denb 512KB  (~23MB)
  // partial[64][8192] (2MB) aliases numb: dead before attn writes numb.
  char* w = (char*)d_ws;
  float* deg  = (float*)w;
  u16*   WT   = (u16*)(w + 32768);
  u16*   Qb   = (u16*)(w + 32768 + 196608);
  u16*   Kb   = Qb + NEL;
  u16*   VT   = Kb + NEL;
  float* numb = (float*)(VT + NEL);
  float* denb = numb + 4*NEL;
  float* partial = numb;

  prep_kernel<<<160, 256, 0, stream>>>(eab, eba, partial, Wq, Wk, Wv, Wo, W1, W2, WT);
  ln_qkv_kernel<<<512, 512, 0, stream>>>(xa, xb, ga, ba, WT, bq, bk, bv,
                                         partial, deg, Qb, Kb, VT);
  attn_kernel<<<dim3(64,4,8), 256, 0, stream>>>(Qb, Kb, VT, numb, denb);
  tail_kernel<<<512, 512, 0, stream>>>(numb, denb, WT, bo, deg, xa, xb,
                                       gfn, bfn, gf, bf, b1, b2, out);
}

// Round 7
// 180.244 us; speedup vs baseline: 1.0237x; 1.0237x over previous
//
#include <hip/hip_runtime.h>

typedef unsigned short u16;
typedef unsigned int   u32;
typedef __attribute__((ext_vector_type(8))) short bf16x8;  // 8 bf16 (4 VGPRs)
typedef __attribute__((ext_vector_type(4))) float f32x4;   // MFMA acc

#define NEL (8192*128)

// async global->LDS, 16B per lane, LDS dest = wave-uniform base + lane*16
#define ASYNC16(ldsptr, gptr) __builtin_amdgcn_global_load_lds( \
    (const __attribute__((address_space(1))) u32*)(gptr), \
    (__attribute__((address_space(3))) u32*)(ldsptr), 16, 0, 0)

__device__ __forceinline__ u16 f2bf(float f){
  u32 u = __builtin_bit_cast(u32, f);
  u = (u + 0x7FFFu + ((u >> 16) & 1u)) >> 16;  // RNE
  return (u16)u;
}
__device__ __forceinline__ u32 pk2(float a, float b){  // lo=bf16(a), hi=bf16(b)
  u32 r;
  asm("v_cvt_pk_bf16_f32 %0, %1, %2" : "=v"(r) : "v"(a), "v"(b));
  return r;
}

// ---------------- prep ----------------
// blocks 0..63: LDS histogram of degrees -> partial[b][8192] (NO global atomics)
// blocks 64..159: weight bf16 transpose WT[6][128][128], WT[w][n][k] = W_w[k][n]
__global__ __launch_bounds__(256) void prep_kernel(
    const int* __restrict__ eab, const int* __restrict__ eba, float* __restrict__ partial,
    const float* __restrict__ Wq, const float* __restrict__ Wk, const float* __restrict__ Wv,
    const float* __restrict__ Wo, const float* __restrict__ W1, const float* __restrict__ W2,
    u16* __restrict__ WT)
{
  __shared__ u32 hist[8192];
  __shared__ float tile[32][33];
  const int b = blockIdx.x, t = threadIdx.x;
  if (b < 64){
    #pragma unroll
    for (int i=0;i<32;i++) hist[t + i*256] = 0u;
    __syncthreads();
    const int e0 = b*1024;
    #pragma unroll
    for (int i=0;i<4;i++){
      int e = e0 + t + i*256;
      atomicAdd(&hist[eab[e]],              1u);  // edge_ab src -> deg_a
      atomicAdd(&hist[4096 + eab[65536+e]], 1u);  // edge_ab dst -> deg_b
      atomicAdd(&hist[4096 + eba[e]],       1u);  // edge_ba src -> deg_b
      atomicAdd(&hist[eba[65536+e]],        1u);  // edge_ba dst -> deg_a
    }
    __syncthreads();
    #pragma unroll
    for (int i=0;i<32;i++){
      int bin = t + i*256;
      partial[b*8192 + bin] = (float)hist[bin];
    }
  } else {
    int id = b - 64;                  // 0..95 = 6 W x 16 tiles(32x32)
    int w = id >> 4, tt = id & 15, tr = tt >> 2, tc = tt & 3;
    const float* W = (w==0)?Wq:(w==1)?Wk:(w==2)?Wv:(w==3)?Wo:(w==4)?W1:W2;
    int r = t >> 3, c4 = (t&7)*4;
    float4 v = *(const float4*)(W + (tr*32 + r)*128 + tc*32 + c4);
    tile[r][c4]=v.x; tile[r][c4+1]=v.y; tile[r][c4+2]=v.z; tile[r][c4+3]=v.w;
    __syncthreads();
    int n = t >> 3, k4 = (t&7)*4;     // write WT[w][tc*32+n][tr*32+k4..+3]
    u32 lo = pk2(tile[k4+0][n], tile[k4+1][n]);
    u32 hi = pk2(tile[k4+2][n], tile[k4+3][n]);
    *(uint2*)(WT + w*16384 + (tc*32+n)*128 + tr*32 + k4) = make_uint2(lo, hi);
  }
}

// ---------------- LN(x); MFMA x@{Wq,Wk,Wv}+b -> bf16 Q(pre-scaled),K,V^T ----------------
// 512 blocks x 512 thr (8 waves), 16 rows/block; wave w -> cols 16w..16w+15
// every block also reduces 16 bins of partial[64][8192] -> deg (overlapped, no stragglers)
__global__ __launch_bounds__(512) void ln_qkv_kernel(
    const float* __restrict__ xa, const float* __restrict__ xb,
    const float* __restrict__ g, const float* __restrict__ bvec,
    const u16* __restrict__ WT,
    const float* __restrict__ bq, const float* __restrict__ bk, const float* __restrict__ bv,
    const float* __restrict__ partial, float* __restrict__ deg,
    u16* __restrict__ Qb, u16* __restrict__ Kb, u16* __restrict__ VT)
{
  __shared__ float xs[16][132];
  __shared__ __align__(16) u16 abf[16][128];   // bf16 A-tile, 16B chunks XOR-swizzled
  __shared__ __align__(16) u16 vtb[128][24];   // V^T bounce (stride 48B)
  const int t = threadIdx.x, lane = t&63, wave = t>>6;
  const int lq = lane&15, lg = lane>>4;
  const int row0 = blockIdx.x*16;
  const float* x = (row0 < 4096) ? (xa + row0*128) : (xb + (row0-4096)*128);
  if (t < 16){ // deg reduce: 16 bins/block, overlaps with staging below
    int bin = blockIdx.x*16 + t;
    float s = 0.f;
    #pragma unroll
    for (int j=0;j<64;j++) s += partial[j*8192 + bin];
    deg[bin] = s;
  }
  { // stage 16x128 f32: one float4/thread
    int r = t>>5, c4 = (t&31)*4;
    float4 v = *(const float4*)(x + r*128 + c4);
    xs[r][c4]=v.x; xs[r][c4+1]=v.y; xs[r][c4+2]=v.z; xs[r][c4+3]=v.w;
  }
  __syncthreads();
  if (t < 256){ // LN, 16 threads/row; write bf16 swizzled A-tile
    int r = t>>4, c0 = t&15;
    float s=0.f, s2=0.f;
    #pragma unroll
    for (int j=0;j<8;j++){ float v = xs[r][c0+j*16]; s+=v; s2+=v*v; }
    #pragma unroll
    for (int m=1;m<16;m<<=1){ s += __shfl_xor(s,m); s2 += __shfl_xor(s2,m); }
    float mean = s*0.0078125f;
    float var  = s2*0.0078125f - mean*mean;
    float rstd = rsqrtf(var + 1e-5f);
    #pragma unroll
    for (int j=0;j<8;j++){
      int c = c0 + j*16;
      float h = (xs[r][c]-mean)*rstd*g[c] + bvec[c];
      int sj = (c>>3) ^ (r&7);
      abf[r][sj*8 + (c&7)] = f2bf(h);
    }
  }
  __syncthreads();
  // A-frags: row=lq, k=s*32+lg*8
  bf16x8 af[4];
  #pragma unroll
  for (int s=0;s<4;s++){
    int sj = (s*4+lg) ^ (lq&7);
    af[s] = *(const bf16x8*)&abf[lq][sj*8];
  }
  const int cb = wave*16;
  const float QSC = 0.17677669529663687f * 1.4426950408889634f; // 1/sqrt(32)*log2e
  #pragma unroll
  for (int m=0;m<3;m++){
    const u16* Wg = WT + m*16384;
    bf16x8 bfr[4];
    #pragma unroll
    for (int s=0;s<4;s++)
      bfr[s] = *(const bf16x8*)(Wg + (cb+lq)*128 + s*32 + lg*8);
    f32x4 acc = {0,0,0,0};
    #pragma unroll
    for (int s=0;s<4;s++)
      acc = __builtin_amdgcn_mfma_f32_16x16x32_bf16(af[s], bfr[s], acc, 0,0,0);
    int col = cb + lq;
    if (m==0){
      float bb = bq[col];
      #pragma unroll
      for (int r=0;r<4;r++)
        Qb[(row0+4*lg+r)*128 + col] = f2bf((acc[r]+bb)*QSC);
    } else if (m==1){
      float bb = bk[col];
      #pragma unroll
      for (int r=0;r<4;r++)
        Kb[(row0+4*lg+r)*128 + col] = f2bf(acc[r]+bb);
    } else {
      float bb = bv[col];
      #pragma unroll
      for (int r=0;r<4;r++)
        vtb[col][4*lg+r] = f2bf(acc[r]+bb);
    }
  }
  __syncthreads();
  if (t < 256){ // V^T global write: c = t>>1, half = t&1 (16B each)
    int c = t>>1, half = t&1;
    bf16x8 v = *(const bf16x8*)&vtb[c][half*8];
    *(bf16x8*)(VT + c*8192 + row0 + half*8) = v;
  }
}

// ---------------- flash attention: per-head, KV-split x4, m==0 softmax ----------------
// grid (64, 4 heads, 8 = dir*4+split); block 256 = 4 waves x 16 q; KBLK=64, 16 tiles.
// 3-buffer counted-vmcnt pipeline: ONE barrier/tile, vmcnt(2) steady state (T3/T4),
// issue(t+2) after barrier (readers of buf[(t+2)%3] finished a barrier ago -> race-free).
__global__ __launch_bounds__(256) void attn_kernel(
    const u16* __restrict__ Qb, const u16* __restrict__ Kb,
    const u16* __restrict__ VT, float* __restrict__ numb, float* __restrict__ denb)
{
  __shared__ __align__(16) u16 Klds[3][2048];   // 64 keys x 4 chunks(16B) each buf
  __shared__ __align__(16) u16 Vlds[3][2048];   // 32 d x 8 chunks each buf
  __shared__ __align__(16) u16 Plds[4][1024];   // per wave: 16 q x 8 chunks
  const int t = threadIdx.x, wave = t>>6, lane = t&63;
  const int lq = lane&15, lg = lane>>4;
  const int h = blockIdx.y;
  const int dir = blockIdx.z >> 2, sp = blockIdx.z & 3;
  const int q = blockIdx.x*64 + wave*16 + lq + (dir ? 4096 : 0);
  const int kvb = (dir ? 0 : 4096) + sp*1024;

  bf16x8 qf = *(const bf16x8*)(Qb + q*128 + h*32 + lg*8);
  f32x4 acc0 = {0,0,0,0}, acc1 = {0,0,0,0}, accL = {0,0,0,0};
  bf16x8 ones;
  #pragma unroll
  for (int i=0;i<8;i++) ones[i] = (short)0x3F80;

  // staging sources: K thread t -> key=t>>2, chunk j=t&3, src cc = j ^ ((key>>1)&3)
  //                  V thread t -> d=t>>3, chunk j=t&7,  src cc = j ^ (d&7)
  const u16* gk = Kb + (kvb + (t>>2))*128 + h*32 + ((t&3) ^ ((t>>3)&3))*8;
  const u16* gv = VT + (h*32 + (t>>3))*8192 + kvb + ((t&7) ^ ((t>>3)&7))*8;

  // prologue: tiles 0,1 in flight (4 outstanding)
  ASYNC16(&Klds[0][t*8], gk);
  ASYNC16(&Vlds[0][t*8], gv);
  ASYNC16(&Klds[1][t*8], gk + 8192);
  ASYNC16(&Vlds[1][t*8], gv + 64);

  #pragma unroll
  for (int kt=0; kt<16; ++kt){
    const int cur = kt % 3;
    // tile kt's 2 loads are the oldest; keep tile kt+1's 2 in flight
    if (kt == 15) asm volatile("s_waitcnt vmcnt(0)" ::: "memory");
    else          asm volatile("s_waitcnt vmcnt(2)" ::: "memory");
    __builtin_amdgcn_s_barrier();
    __builtin_amdgcn_sched_barrier(0);
    if (kt < 14){
      const int nb = (kt+2) % 3;
      ASYNC16(&Klds[nb][t*8], gk + (kt+2)*8192);
      ASYNC16(&Vlds[nb][t*8], gv + (kt+2)*64);
    }
    const u16* KL = Klds[cur];
    const u16* VL = Vlds[cur];
    u16* PL = Plds[wave] + lq*64;
    // S^T (4 MFMA) -> exp2 -> pack -> P LDS
    const int ksj = lg ^ ((lq>>1)&3);
    #pragma unroll
    for (int f=0; f<4; ++f){
      bf16x8 kf = *(const bf16x8*)(KL + (f*16+lq)*32 + ksj*8);
      f32x4 st = __builtin_amdgcn_mfma_f32_16x16x32_bf16(kf, qf, (f32x4){0.f,0.f,0.f,0.f}, 0,0,0);
      float p0 = __builtin_amdgcn_exp2f(st[0]);
      float p1 = __builtin_amdgcn_exp2f(st[1]);
      float p2 = __builtin_amdgcn_exp2f(st[2]);
      float p3 = __builtin_amdgcn_exp2f(st[3]);
      int j = f*2 + (lg>>1);
      *(uint2*)(PL + ((j ^ (lq&7))<<3) + (lg&1)*4) = make_uint2(pk2(p0,p1), pk2(p2,p3));
    }
    // PV + l-sum: 6 MFMA
    __builtin_amdgcn_s_setprio(1);
    #pragma unroll
    for (int kc=0; kc<2; ++kc){
      int sj = (kc*4+lg) ^ (lq&7);
      bf16x8 pf  = *(const bf16x8*)(PL + (sj<<3));
      bf16x8 vf0 = *(const bf16x8*)(VL + lq*64      + (sj<<3));
      bf16x8 vf1 = *(const bf16x8*)(VL + (16+lq)*64 + (sj<<3));
      acc0 = __builtin_amdgcn_mfma_f32_16x16x32_bf16(vf0,  pf, acc0, 0,0,0);
      acc1 = __builtin_amdgcn_mfma_f32_16x16x32_bf16(vf1,  pf, acc1, 0,0,0);
      accL = __builtin_amdgcn_mfma_f32_16x16x32_bf16(ones, pf, accL, 0,0,0);
    }
    __builtin_amdgcn_s_setprio(0);
  }
  float* outp = numb + sp*NEL + q*128 + h*32 + 4*lg;   // d = h*32 + 4lg + r
  *(float4*)(outp)      = make_float4(acc0[0], acc0[1], acc0[2], acc0[3]);
  *(float4*)(outp + 16) = make_float4(acc1[0], acc1[1], acc1[2], acc1[3]);
  if (lg == 0) denb[sp*32768 + q*4 + h] = accL[0];
}

// ---------------- MFMA tail: combine splits; @Wo+bo+deg+x -> res ; LN;LN ; @W1+gelu ; @W2+b2+res ----------------
// 512 blocks x 512 thr (8 waves), 16 rows; wave w -> cols 16w..+15
__global__ __launch_bounds__(512) void tail_kernel(
    const float* __restrict__ numb, const float* __restrict__ denb,
    const u16* __restrict__ WT,
    const float* __restrict__ bo, const float* __restrict__ deg,
    const float* __restrict__ xa, const float* __restrict__ xb,
    const float* __restrict__ gf1, const float* __restrict__ bf1,
    const float* __restrict__ gf2, const float* __restrict__ bf2,
    const float* __restrict__ b1, const float* __restrict__ b2,
    float* __restrict__ out)
{
  __shared__ __align__(16) u16 abf[16][128];
  __shared__ float rs[16][132];
  const int t = threadIdx.x, lane = t&63, wave = t>>6;
  const int lq = lane&15, lg = lane>>4;
  const int row0 = blockIdx.x*16;
  const int cb = wave*16;

  { // combine 4 KV-split partials, normalize, -> bf16 swizzled A-tile
    int r = t>>5, c0 = (t&31)*4, hh = c0>>5;
    const float* np = numb + (row0+r)*128 + c0;
    float4 s0 = *(const float4*)(np);
    float4 s1 = *(const float4*)(np + NEL);
    float4 s2 = *(const float4*)(np + 2*NEL);
    float4 s3 = *(const float4*)(np + 3*NEL);
    int di = (row0+r)*4 + hh;
    float den = denb[di] + denb[32768+di] + denb[65536+di] + denb[98304+di];
    float inv = 1.0f/den;
    float a0 = (s0.x+s1.x+s2.x+s3.x)*inv;
    float a1 = (s0.y+s1.y+s2.y+s3.y)*inv;
    float a2 = (s0.z+s1.z+s2.z+s3.z)*inv;
    float a3 = (s0.w+s1.w+s2.w+s3.w)*inv;
    int sj = (c0>>3) ^ (r&7);
    *(uint2*)&abf[r][sj*8 + (c0&7)] = make_uint2(pk2(a0,a1), pk2(a2,a3));
  }
  __syncthreads();

  bf16x8 af[4];
  #pragma unroll
  for (int s=0;s<4;s++){ int sj = (s*4+lg) ^ (lq&7); af[s] = *(const bf16x8*)&abf[lq][sj*8]; }

  // GEMM1: @Wo
  f32x4 acc = {0,0,0,0};
  {
    const u16* Wg = WT + 3*16384;
    bf16x8 bfr[4];
    #pragma unroll
    for (int s=0;s<4;s++) bfr[s] = *(const bf16x8*)(Wg + (cb+lq)*128 + s*32 + lg*8);
    #pragma unroll
    for (int s=0;s<4;s++) acc = __builtin_amdgcn_mfma_f32_16x16x32_bf16(af[s], bfr[s], acc, 0,0,0);
  }
  // epilogue1: res = c + bo + deg + x
  const float* xres = (row0<4096)? (xa + row0*128) : (xb + (row0-4096)*128);
  const int col = cb + lq;
  float rv[4];
  {
    float bb = bo[col];
    #pragma unroll
    for (int r=0;r<4;r++){
      int lr = 4*lg + r;
      rv[r] = acc[r] + bb + deg[row0+lr] + xres[lr*128 + col];
      rs[lr][col] = rv[r];
    }
  }
  __syncthreads();
  if (t < 256){ // LN(gf1) then LN(gf2); write bf16 swizzled into abf
    int r = t>>4, c0 = t&15;
    float s=0.f, s2=0.f;
    #pragma unroll
    for (int j=0;j<8;j++){ float v = rs[r][c0+j*16]; s+=v; s2+=v*v; }
    #pragma unroll
    for (int m=1;m<16;m<<=1){ s += __shfl_xor(s,m); s2 += __shfl_xor(s2,m); }
    float mean = s*0.0078125f;
    float var  = s2*0.0078125f - mean*mean;
    float rstd = rsqrtf(var + 1e-5f);
    float h8[8];
    #pragma unroll
    for (int j=0;j<8;j++){ int c=c0+j*16; h8[j] = (rs[r][c]-mean)*rstd*gf1[c] + bf1[c]; }
    s=0.f; s2=0.f;
    #pragma unroll
    for (int j=0;j<8;j++){ s+=h8[j]; s2+=h8[j]*h8[j]; }
    #pragma unroll
    for (int m=1;m<16;m<<=1){ s += __shfl_xor(s,m); s2 += __shfl_xor(s2,m); }
    float mean2 = s*0.0078125f;
    float var2  = s2*0.0078125f - mean2*mean2;
    float rstd2 = rsqrtf(var2 + 1e-5f);
    #pragma unroll
    for (int j=0;j<8;j++){
      int c = c0 + j*16;
      float h = (h8[j]-mean2)*rstd2*gf2[c] + bf2[c];
      int sj = (c>>3) ^ (r&7);
      abf[r][sj*8 + (c&7)] = f2bf(h);
    }
  }
  __syncthreads();
  // GEMM2: @W1 -> gelu
  #pragma unroll
  for (int s=0;s<4;s++){ int sj = (s*4+lg) ^ (lq&7); af[s] = *(const bf16x8*)&abf[lq][sj*8]; }
  acc = (f32x4){0,0,0,0};
  {
    const u16* Wg = WT + 4*16384;
    bf16x8 bfr[4];
    #pragma unroll
    for (int s=0;s<4;s++) bfr[s] = *(const bf16x8*)(Wg + (cb+lq)*128 + s*32 + lg*8);
    #pragma unroll
    for (int s=0;s<4;s++) acc = __builtin_amdgcn_mfma_f32_16x16x32_bf16(af[s], bfr[s], acc, 0,0,0);
  }
  float gvv[4];
  {
    float bb = b1[col];
    #pragma unroll
    for (int r=0;r<4;r++){
      float v = acc[r] + bb;
      gvv[r] = 0.5f*v*(1.f + erff(v*0.70710678118654752f));
    }
  }
  __syncthreads();   // all GEMM2 A-reads done before overwrite
  #pragma unroll
  for (int r=0;r<4;r++){
    int lr = 4*lg + r;
    int sj = (col>>3) ^ (lr&7);
    abf[lr][sj*8 + (col&7)] = f2bf(gvv[r]);
  }
  __syncthreads();
  // GEMM3: @W2 + b2 + res -> out
  #pragma unroll
  for (int s=0;s<4;s++){ int sj = (s*4+lg) ^ (lq&7); af[s] = *(const bf16x8*)&abf[lq][sj*8]; }
  acc = (f32x4){0,0,0,0};
  {
    const u16* Wg = WT + 5*16384;
    bf16x8 bfr[4];
    #pragma unroll
    for (int s=0;s<4;s++) bfr[s] = *(const bf16x8*)(Wg + (cb+lq)*128 + s*32 + lg*8);
    #pragma unroll
    for (int s=0;s<4;s++) acc = __builtin_amdgcn_mfma_f32_16x16x32_bf16(af[s], bfr[s], acc, 0,0,0);
  }
  {
    float bb = b2[col];
    #pragma unroll
    for (int r=0;r<4;r++){
      int lr = 4*lg + r;
      out[(row0+lr)*128 + col] = acc[r] + bb + rv[r];
    }
  }
}

extern "C" void kernel_launch(void* const* d_in, const int* in_sizes, int n_in,
                              void* d_out, int out_size, void* d_ws, size_t ws_size,
                              hipStream_t stream) {
  const float* xa  = (const float*)d_in[0];
  const float* xb  = (const float*)d_in[1];
  const int*   eab = (const int*)d_in[2];
  const int*   eba = (const int*)d_in[3];
  const float* Wq  = (const float*)d_in[4];   const float* bq = (const float*)d_in[5];
  const float* Wk  = (const float*)d_in[6];   const float* bk = (const float*)d_in[7];
  const float* Wv  = (const float*)d_in[8];   const float* bv = (const float*)d_in[9];
  const float* Wo  = (const float*)d_in[10];  const float* bo = (const float*)d_in[11];
  const float* ga  = (const float*)d_in[12];  const float* ba = (const float*)d_in[13];
  const float* gfn = (const float*)d_in[14];  const float* bfn= (const float*)d_in[15];
  const float* gf  = (const float*)d_in[16];  const float* bf = (const float*)d_in[17];
  const float* W1  = (const float*)d_in[18];  const float* b1 = (const float*)d_in[19];
  const float* W2  = (const float*)d_in[20];  const float* b2 = (const float*)d_in[21];
  float* out = (float*)d_out;

  // ws: deg 32KB | WT 192KB | Qb,Kb,VT 2MB each | numb 16MB | denb 512KB  (~23MB)
  // partial[64][8192] (2MB) aliases numb: dead before attn writes numb.
  char* w = (char*)d_ws;
  float* deg  = (float*)w;
  u16*   WT   = (u16*)(w + 32768);
  u16*   Qb   = (u16*)(w + 32768 + 196608);
  u16*   Kb   = Qb + NEL;
  u16*   VT   = Kb + NEL;
  float* numb = (float*)(VT + NEL);
  float* denb = numb + 4*NEL;
  float* partial = numb;

  prep_kernel<<<160, 256, 0, stream>>>(eab, eba, partial, Wq, Wk, Wv, Wo, W1, W2, WT);
  ln_qkv_kernel<<<512, 512, 0, stream>>>(xa, xb, ga, ba, WT, bq, bk, bv,
                                         partial, deg, Qb, Kb, VT);
  attn_kernel<<<dim3(64,4,8), 256, 0, stream>>>(Qb, Kb, VT, numb, denb);
  tail_kernel<<<512, 512, 0, stream>>>(numb, denb, WT, bo, deg, xa, xb,
                                       gfn, bfn, gf, bf, b1, b2, out);
}

// Round 9
// 176.718 us; speedup vs baseline: 1.0442x; 1.0200x over previous
//
#include <hip/hip_runtime.h>

typedef unsigned short u16;
typedef unsigned int   u32;
typedef __attribute__((ext_vector_type(8))) short bf16x8;  // 8 bf16 (4 VGPRs)
typedef __attribute__((ext_vector_type(4))) float f32x4;   // MFMA acc

#define NEL (8192*128)

// async global->LDS, 16B per lane, LDS dest = wave-uniform base + lane*16
#define ASYNC16(ldsptr, gptr) __builtin_amdgcn_global_load_lds( \
    (const __attribute__((address_space(1))) u32*)(gptr), \
    (__attribute__((address_space(3))) u32*)(ldsptr), 16, 0, 0)

__device__ __forceinline__ u16 f2bf(float f){
  u32 u = __builtin_bit_cast(u32, f);
  u = (u + 0x7FFFu + ((u >> 16) & 1u)) >> 16;  // RNE
  return (u16)u;
}
__device__ __forceinline__ u32 pk2(float a, float b){  // lo=bf16(a), hi=bf16(b)
  u32 r;
  asm("v_cvt_pk_bf16_f32 %0, %1, %2" : "=v"(r) : "v"(a), "v"(b));
  return r;
}

// ---------------- prep ----------------
// blocks 0..63: LDS histogram of degrees -> partial[b][8192] (NO global atomics)
// blocks 64..159: weight bf16 transpose WT[6][128][128], WT[w][n][k] = W_w[k][n]
__global__ __launch_bounds__(256) void prep_kernel(
    const int* __restrict__ eab, const int* __restrict__ eba, float* __restrict__ partial,
    const float* __restrict__ Wq, const float* __restrict__ Wk, const float* __restrict__ Wv,
    const float* __restrict__ Wo, const float* __restrict__ W1, const float* __restrict__ W2,
    u16* __restrict__ WT)
{
  __shared__ u32 hist[8192];
  __shared__ float tile[32][33];
  const int b = blockIdx.x, t = threadIdx.x;
  if (b < 64){
    #pragma unroll
    for (int i=0;i<32;i++) hist[t + i*256] = 0u;
    __syncthreads();
    const int e0 = b*1024;
    #pragma unroll
    for (int i=0;i<4;i++){
      int e = e0 + t + i*256;
      atomicAdd(&hist[eab[e]],              1u);  // edge_ab src -> deg_a
      atomicAdd(&hist[4096 + eab[65536+e]], 1u);  // edge_ab dst -> deg_b
      atomicAdd(&hist[4096 + eba[e]],       1u);  // edge_ba src -> deg_b
      atomicAdd(&hist[eba[65536+e]],        1u);  // edge_ba dst -> deg_a
    }
    __syncthreads();
    #pragma unroll
    for (int i=0;i<32;i++){
      int bin = t + i*256;
      partial[b*8192 + bin] = (float)hist[bin];
    }
  } else {
    int id = b - 64;                  // 0..95 = 6 W x 16 tiles(32x32)
    int w = id >> 4, tt = id & 15, tr = tt >> 2, tc = tt & 3;
    const float* W = (w==0)?Wq:(w==1)?Wk:(w==2)?Wv:(w==3)?Wo:(w==4)?W1:W2;
    int r = t >> 3, c4 = (t&7)*4;
    float4 v = *(const float4*)(W + (tr*32 + r)*128 + tc*32 + c4);
    tile[r][c4]=v.x; tile[r][c4+1]=v.y; tile[r][c4+2]=v.z; tile[r][c4+3]=v.w;
    __syncthreads();
    int n = t >> 3, k4 = (t&7)*4;     // write WT[w][tc*32+n][tr*32+k4..+3]
    u32 lo = pk2(tile[k4+0][n], tile[k4+1][n]);
    u32 hi = pk2(tile[k4+2][n], tile[k4+3][n]);
    *(uint2*)(WT + w*16384 + (tc*32+n)*128 + tr*32 + k4) = make_uint2(lo, hi);
  }
}

// ---------------- LN(x); MFMA x@{Wq,Wk,Wv}+b -> bf16 Q(pre-scaled),K,V^T ----------------
// 512 blocks x 512 thr (8 waves), 16 rows/block; wave w -> cols 16w..16w+15
// every block also reduces 16 bins of partial[64][8192] -> deg (overlapped, no stragglers)
__global__ __launch_bounds__(512) void ln_qkv_kernel(
    const float* __restrict__ xa, const float* __restrict__ xb,
    const float* __restrict__ g, const float* __restrict__ bvec,
    const u16* __restrict__ WT,
    const float* __restrict__ bq, const float* __restrict__ bk, const float* __restrict__ bv,
    const float* __restrict__ partial, float* __restrict__ deg,
    u16* __restrict__ Qb, u16* __restrict__ Kb, u16* __restrict__ VT)
{
  __shared__ float xs[16][132];
  __shared__ __align__(16) u16 abf[16][128];   // bf16 A-tile, 16B chunks XOR-swizzled
  __shared__ __align__(16) u16 vtb[128][24];   // V^T bounce (stride 48B)
  const int t = threadIdx.x, lane = t&63, wave = t>>6;
  const int lq = lane&15, lg = lane>>4;
  const int row0 = blockIdx.x*16;
  const float* x = (row0 < 4096) ? (xa + row0*128) : (xb + (row0-4096)*128);
  if (t < 16){ // deg reduce: 16 bins/block, overlaps with staging below
    int bin = blockIdx.x*16 + t;
    float s = 0.f;
    #pragma unroll
    for (int j=0;j<64;j++) s += partial[j*8192 + bin];
    deg[bin] = s;
  }
  { // stage 16x128 f32: one float4/thread
    int r = t>>5, c4 = (t&31)*4;
    float4 v = *(const float4*)(x + r*128 + c4);
    xs[r][c4]=v.x; xs[r][c4+1]=v.y; xs[r][c4+2]=v.z; xs[r][c4+3]=v.w;
  }
  __syncthreads();
  if (t < 256){ // LN, 16 threads/row; write bf16 swizzled A-tile
    int r = t>>4, c0 = t&15;
    float s=0.f, s2=0.f;
    #pragma unroll
    for (int j=0;j<8;j++){ float v = xs[r][c0+j*16]; s+=v; s2+=v*v; }
    #pragma unroll
    for (int m=1;m<16;m<<=1){ s += __shfl_xor(s,m); s2 += __shfl_xor(s2,m); }
    float mean = s*0.0078125f;
    float var  = s2*0.0078125f - mean*mean;
    float rstd = rsqrtf(var + 1e-5f);
    #pragma unroll
    for (int j=0;j<8;j++){
      int c = c0 + j*16;
      float h = (xs[r][c]-mean)*rstd*g[c] + bvec[c];
      int sj = (c>>3) ^ (r&7);
      abf[r][sj*8 + (c&7)] = f2bf(h);
    }
  }
  __syncthreads();
  // A-frags: row=lq, k=s*32+lg*8
  bf16x8 af[4];
  #pragma unroll
  for (int s=0;s<4;s++){
    int sj = (s*4+lg) ^ (lq&7);
    af[s] = *(const bf16x8*)&abf[lq][sj*8];
  }
  const int cb = wave*16;
  const float QSC = 0.17677669529663687f * 1.4426950408889634f; // 1/sqrt(32)*log2e
  #pragma unroll
  for (int m=0;m<3;m++){
    const u16* Wg = WT + m*16384;
    bf16x8 bfr[4];
    #pragma unroll
    for (int s=0;s<4;s++)
      bfr[s] = *(const bf16x8*)(Wg + (cb+lq)*128 + s*32 + lg*8);
    f32x4 acc = {0,0,0,0};
    #pragma unroll
    for (int s=0;s<4;s++)
      acc = __builtin_amdgcn_mfma_f32_16x16x32_bf16(af[s], bfr[s], acc, 0,0,0);
    int col = cb + lq;
    if (m==0){
      float bb = bq[col];
      #pragma unroll
      for (int r=0;r<4;r++)
        Qb[(row0+4*lg+r)*128 + col] = f2bf((acc[r]+bb)*QSC);
    } else if (m==1){
      float bb = bk[col];
      #pragma unroll
      for (int r=0;r<4;r++)
        Kb[(row0+4*lg+r)*128 + col] = f2bf(acc[r]+bb);
    } else {
      float bb = bv[col];
      #pragma unroll
      for (int r=0;r<4;r++)
        vtb[col][4*lg+r] = f2bf(acc[r]+bb);
    }
  }
  __syncthreads();
  if (t < 256){ // V^T global write: c = t>>1, half = t&1 (16B each)
    int c = t>>1, half = t&1;
    bf16x8 v = *(const bf16x8*)&vtb[c][half*8];
    *(bf16x8*)(VT + c*8192 + row0 + half*8) = v;
  }
}

// ---------------- flash attention: per-head, KV-split x4, 32 q/wave, m==0 softmax ----------------
// grid (32, 4 heads, 8 = dir*4+split); block 256 = 4 waves x 32 q = 128 q/block; KBLK=64, 16 tiles.
// Two q-halves per wave: each K/V fragment read feeds 2 MFMAs (fragment reuse),
// 2 independent dep chains (ILP). 3-buffer counted-vmcnt pipeline, 1 barrier/tile.
__global__ __launch_bounds__(256) void attn_kernel(
    const u16* __restrict__ Qb, const u16* __restrict__ Kb,
    const u16* __restrict__ VT, float* __restrict__ numb, float* __restrict__ denb)
{
  __shared__ __align__(16) u16 Klds[3][2048];   // 64 keys x 4 chunks(16B) each buf
  __shared__ __align__(16) u16 Vlds[3][2048];   // 32 d x 8 chunks each buf
  __shared__ __align__(16) u16 Plds[4][2048];   // per wave: 32 q x 8 chunks
  const int t = threadIdx.x, wave = t>>6, lane = t&63;
  const int lq = lane&15, lg = lane>>4;
  const int h = blockIdx.y;
  const int dir = blockIdx.z >> 2, sp = blockIdx.z & 3;
  const int qb = blockIdx.x*128 + wave*32 + (dir ? 4096 : 0);
  const int q0 = qb + lq, q1 = qb + 16 + lq;
  const int kvb = (dir ? 0 : 4096) + sp*1024;

  bf16x8 qf0 = *(const bf16x8*)(Qb + q0*128 + h*32 + lg*8);
  bf16x8 qf1 = *(const bf16x8*)(Qb + q1*128 + h*32 + lg*8);
  f32x4 a00 = {0,0,0,0}, a01 = {0,0,0,0}, aL0 = {0,0,0,0};
  f32x4 a10 = {0,0,0,0}, a11 = {0,0,0,0}, aL1 = {0,0,0,0};
  bf16x8 ones;
  #pragma unroll
  for (int i=0;i<8;i++) ones[i] = (short)0x3F80;

  // staging sources: K thread t -> key=t>>2, chunk j=t&3, src cc = j ^ ((key>>1)&3)
  //                  V thread t -> d=t>>3, chunk j=t&7,  src cc = j ^ (d&7)
  const u16* gk = Kb + (kvb + (t>>2))*128 + h*32 + ((t&3) ^ ((t>>3)&3))*8;
  const u16* gv = VT + (h*32 + (t>>3))*8192 + kvb + ((t&7) ^ ((t>>3)&7))*8;

  // prologue: tiles 0,1 in flight (4 outstanding)
  ASYNC16(&Klds[0][t*8], gk);
  ASYNC16(&Vlds[0][t*8], gv);
  ASYNC16(&Klds[1][t*8], gk + 8192);
  ASYNC16(&Vlds[1][t*8], gv + 64);

  #pragma unroll
  for (int kt=0; kt<16; ++kt){
    const int cur = kt % 3;
    // tile kt's 2 loads are the oldest; keep tile kt+1's 2 in flight
    if (kt == 15) asm volatile("s_waitcnt vmcnt(0)" ::: "memory");
    else          asm volatile("s_waitcnt vmcnt(2)" ::: "memory");
    __builtin_amdgcn_s_barrier();
    __builtin_amdgcn_sched_barrier(0);
    if (kt < 14){
      const int nb = (kt+2) % 3;
      ASYNC16(&Klds[nb][t*8], gk + (kt+2)*8192);
      ASYNC16(&Vlds[nb][t*8], gv + (kt+2)*64);
    }
    const u16* KL = Klds[cur];
    const u16* VL = Vlds[cur];
    u16* PL0 = Plds[wave] + lq*64;          // q-half 0 row
    u16* PL1 = Plds[wave] + (16+lq)*64;     // q-half 1 row ((16+lq)&7 == lq&7)
    // S^T (8 MFMA, kf reused x2) -> exp2 -> pack -> P LDS
    const int ksj = lg ^ ((lq>>1)&3);
    #pragma unroll
    for (int f=0; f<4; ++f){
      bf16x8 kf = *(const bf16x8*)(KL + (f*16+lq)*32 + ksj*8);
      f32x4 s0 = __builtin_amdgcn_mfma_f32_16x16x32_bf16(kf, qf0, (f32x4){0.f,0.f,0.f,0.f}, 0,0,0);
      f32x4 s1 = __builtin_amdgcn_mfma_f32_16x16x32_bf16(kf, qf1, (f32x4){0.f,0.f,0.f,0.f}, 0,0,0);
      int j = f*2 + (lg>>1);
      int off = ((j ^ (lq&7))<<3) + (lg&1)*4;
      *(uint2*)(PL0 + off) = make_uint2(
          pk2(__builtin_amdgcn_exp2f(s0[0]), __builtin_amdgcn_exp2f(s0[1])),
          pk2(__builtin_amdgcn_exp2f(s0[2]), __builtin_amdgcn_exp2f(s0[3])));
      *(uint2*)(PL1 + off) = make_uint2(
          pk2(__builtin_amdgcn_exp2f(s1[0]), __builtin_amdgcn_exp2f(s1[1])),
          pk2(__builtin_amdgcn_exp2f(s1[2]), __builtin_amdgcn_exp2f(s1[3])));
    }
    // PV + l-sum: 12 MFMA, vf reused x2
    __builtin_amdgcn_s_setprio(1);
    #pragma unroll
    for (int kc=0; kc<2; ++kc){
      int sj = (kc*4+lg) ^ (lq&7);
      bf16x8 pf0 = *(const bf16x8*)(PL0 + (sj<<3));
      bf16x8 pf1 = *(const bf16x8*)(PL1 + (sj<<3));
      bf16x8 vf0 = *(const bf16x8*)(VL + lq*64      + (sj<<3));
      bf16x8 vf1 = *(const bf16x8*)(VL + (16+lq)*64 + (sj<<3));
      a00 = __builtin_amdgcn_mfma_f32_16x16x32_bf16(vf0,  pf0, a00, 0,0,0);
      a10 = __builtin_amdgcn_mfma_f32_16x16x32_bf16(vf0,  pf1, a10, 0,0,0);
      a01 = __builtin_amdgcn_mfma_f32_16x16x32_bf16(vf1,  pf0, a01, 0,0,0);
      a11 = __builtin_amdgcn_mfma_f32_16x16x32_bf16(vf1,  pf1, a11, 0,0,0);
      aL0 = __builtin_amdgcn_mfma_f32_16x16x32_bf16(ones, pf0, aL0, 0,0,0);
      aL1 = __builtin_amdgcn_mfma_f32_16x16x32_bf16(ones, pf1, aL1, 0,0,0);
    }
    __builtin_amdgcn_s_setprio(0);
  }
  float* o0 = numb + sp*NEL + q0*128 + h*32 + 4*lg;   // d = h*32 + 4lg + r
  *(float4*)(o0)      = make_float4(a00[0], a00[1], a00[2], a00[3]);
  *(float4*)(o0 + 16) = make_float4(a01[0], a01[1], a01[2], a01[3]);
  float* o1 = numb + sp*NEL + q1*128 + h*32 + 4*lg;
  *(float4*)(o1)      = make_float4(a10[0], a10[1], a10[2], a10[3]);
  *(float4*)(o1 + 16) = make_float4(a11[0], a11[1], a11[2], a11[3]);
  if (lg == 0){
    denb[sp*32768 + q0*4 + h] = aL0[0];
    denb[sp*32768 + q1*4 + h] = aL1[0];
  }
}

// ---------------- MFMA tail: combine splits; @Wo+bo+deg+x -> res ; LN;LN ; @W1+gelu ; @W2+b2+res ----------------
// 512 blocks x 512 thr (8 waves), 16 rows; wave w -> cols 16w..+15
__global__ __launch_bounds__(512) void tail_kernel(
    const float* __restrict__ numb, const float* __restrict__ denb,
    const u16* __restrict__ WT,
    const float* __restrict__ bo, const float* __restrict__ deg,
    const float* __restrict__ xa, const float* __restrict__ xb,
    const float* __restrict__ gf1, const float* __restrict__ bf1,
    const float* __restrict__ gf2, const float* __restrict__ bf2,
    const float* __restrict__ b1, const float* __restrict__ b2,
    float* __restrict__ out)
{
  __shared__ __align__(16) u16 abf[16][128];
  __shared__ float rs[16][132];
  const int t = threadIdx.x, lane = t&63, wave = t>>6;
  const int lq = lane&15, lg = lane>>4;
  const int row0 = blockIdx.x*16;
  const int cb = wave*16;

  { // combine 4 KV-split partials, normalize, -> bf16 swizzled A-tile
    int r = t>>5, c0 = (t&31)*4, hh = c0>>5;
    const float* np = numb + (row0+r)*128 + c0;
    float4 s0 = *(const float4*)(np);
    float4 s1 = *(const float4*)(np + NEL);
    float4 s2 = *(const float4*)(np + 2*NEL);
    float4 s3 = *(const float4*)(np + 3*NEL);
    int di = (row0+r)*4 + hh;
    float den = denb[di] + denb[32768+di] + denb[65536+di] + denb[98304+di];
    float inv = 1.0f/den;
    float a0 = (s0.x+s1.x+s2.x+s3.x)*inv;
    float a1 = (s0.y+s1.y+s2.y+s3.y)*inv;
    float a2 = (s0.z+s1.z+s2.z+s3.z)*inv;
    float a3 = (s0.w+s1.w+s2.w+s3.w)*inv;
    int sj = (c0>>3) ^ (r&7);
    *(uint2*)&abf[r][sj*8 + (c0&7)] = make_uint2(pk2(a0,a1), pk2(a2,a3));
  }
  __syncthreads();

  bf16x8 af[4];
  #pragma unroll
  for (int s=0;s<4;s++){ int sj = (s*4+lg) ^ (lq&7); af[s] = *(const bf16x8*)&abf[lq][sj*8]; }

  // GEMM1: @Wo
  f32x4 acc = {0,0,0,0};
  {
    const u16* Wg = WT + 3*16384;
    bf16x8 bfr[4];
    #pragma unroll
    for (int s=0;s<4;s++) bfr[s] = *(const bf16x8*)(Wg + (cb+lq)*128 + s*32 + lg*8);
    #pragma unroll
    for (int s=0;s<4;s++) acc = __builtin_amdgcn_mfma_f32_16x16x32_bf16(af[s], bfr[s], acc, 0,0,0);
  }
  // epilogue1: res = c + bo + deg + x
  const float* xres = (row0<4096)? (xa + row0*128) : (xb + (row0-4096)*128);
  const int col = cb + lq;
  float rv[4];
  {
    float bb = bo[col];
    #pragma unroll
    for (int r=0;r<4;r++){
      int lr = 4*lg + r;
      rv[r] = acc[r] + bb + deg[row0+lr] + xres[lr*128 + col];
      rs[lr][col] = rv[r];
    }
  }
  __syncthreads();
  if (t < 256){ // LN(gf1) then LN(gf2); write bf16 swizzled into abf
    int r = t>>4, c0 = t&15;
    float s=0.f, s2=0.f;
    #pragma unroll
    for (int j=0;j<8;j++){ float v = rs[r][c0+j*16]; s+=v; s2+=v*v; }
    #pragma unroll
    for (int m=1;m<16;m<<=1){ s += __shfl_xor(s,m); s2 += __shfl_xor(s2,m); }
    float mean = s*0.0078125f;
    float var  = s2*0.0078125f - mean*mean;
    float rstd = rsqrtf(var + 1e-5f);
    float h8[8];
    #pragma unroll
    for (int j=0;j<8;j++){ int c=c0+j*16; h8[j] = (rs[r][c]-mean)*rstd*gf1[c] + bf1[c]; }
    s=0.f; s2=0.f;
    #pragma unroll
    for (int j=0;j<8;j++){ s+=h8[j]; s2+=h8[j]*h8[j]; }
    #pragma unroll
    for (int m=1;m<16;m<<=1){ s += __shfl_xor(s,m); s2 += __shfl_xor(s2,m); }
    float mean2 = s*0.0078125f;
    float var2  = s2*0.0078125f - mean2*mean2;
    float rstd2 = rsqrtf(var2 + 1e-5f);
    #pragma unroll
    for (int j=0;j<8;j++){
      int c = c0 + j*16;
      float h = (h8[j]-mean2)*rstd2*gf2[c] + bf2[c];
      int sj = (c>>3) ^ (r&7);
      abf[r][sj*8 + (c&7)] = f2bf(h);
    }
  }
  __syncthreads();
  // GEMM2: @W1 -> gelu
  #pragma unroll
  for (int s=0;s<4;s++){ int sj = (s*4+lg) ^ (lq&7); af[s] = *(const bf16x8*)&abf[lq][sj*8]; }
  acc = (f32x4){0,0,0,0};
  {
    const u16* Wg = WT + 4*16384;
    bf16x8 bfr[4];
    #pragma unroll
    for (int s=0;s<4;s++) bfr[s] = *(const bf16x8*)(Wg + (cb+lq)*128 + s*32 + lg*8);
    #pragma unroll
    for (int s=0;s<4;s++) acc = __builtin_amdgcn_mfma_f32_16x16x32_bf16(af[s], bfr[s], acc, 0,0,0);
  }
  float gvv[4];
  {
    float bb = b1[col];
    #pragma unroll
    for (int r=0;r<4;r++){
      float v = acc[r] + bb;
      gvv[r] = 0.5f*v*(1.f + erff(v*0.70710678118654752f));
    }
  }
  __syncthreads();   // all GEMM2 A-reads done before overwrite
  #pragma unroll
  for (int r=0;r<4;r++){
    int lr = 4*lg + r;
    int sj = (col>>3) ^ (lr&7);
    abf[lr][sj*8 + (col&7)] = f2bf(gvv[r]);
  }
  __syncthreads();
  // GEMM3: @W2 + b2 + res -> out
  #pragma unroll
  for (int s=0;s<4;s++){ int sj = (s*4+lg) ^ (lq&7); af[s] = *(const bf16x8*)&abf[lq][sj*8]; }
  acc = (f32x4){0,0,0,0};
  {
    const u16* Wg = WT + 5*16384;
    bf16x8 bfr[4];
    #pragma unroll
    for (int s=0;s<4;s++) bfr[s] = *(const bf16x8*)(Wg + (cb+lq)*128 + s*32 + lg*8);
    #pragma unroll
    for (int s=0;s<4;s++) acc = __builtin_amdgcn_mfma_f32_16x16x32_bf16(af[s], bfr[s], acc, 0,0,0);
  }
  {
    float bb = b2[col];
    #pragma unroll
    for (int r=0;r<4;r++){
      int lr = 4*lg + r;
      out[(row0+lr)*128 + col] = acc[r] + bb + rv[r];
    }
  }
}

extern "C" void kernel_launch(void* const* d_in, const int* in_sizes, int n_in,
                              void* d_out, int out_size, void* d_ws, size_t ws_size,
                              hipStream_t stream) {
  const float* xa  = (const float*)d_in[0];
  const float* xb  = (const float*)d_in[1];
  const int*   eab = (const int*)d_in[2];
  const int*   eba = (const int*)d_in[3];
  const float* Wq  = (const float*)d_in[4];   const float* bq = (const float*)d_in[5];
  const float* Wk  = (const float*)d_in[6];   const float* bk = (const float*)d_in[7];
  const float* Wv  = (const float*)d_in[8];   const float* bv = (const float*)d_in[9];
  const float* Wo  = (const float*)d_in[10];  const float* bo = (const float*)d_in[11];
  const float* ga  = (const float*)d_in[12];  const float* ba = (const float*)d_in[13];
  const float* gfn = (const float*)d_in[14];  const float* bfn= (const float*)d_in[15];
  const float* gf  = (const float*)d_in[16];  const float* bf = (const float*)d_in[17];
  const float* W1  = (const float*)d_in[18];  const float* b1 = (const float*)d_in[19];
  const float* W2  = (const float*)d_in[20];  const float* b2 = (const float*)d_in[21];
  float* out = (float*)d_out;

  // ws: deg 32KB | WT 192KB | Qb,Kb,VT 2MB each | numb 16MB | denb 512KB  (~23MB)
  // partial[64][8192] (2MB) aliases numb: dead before attn writes numb.
  char* w = (char*)d_ws;
  float* deg  = (float*)w;
  u16*   WT   = (u16*)(w + 32768);
  u16*   Qb   = (u16*)(w + 32768 + 196608);
  u16*   Kb   = Qb + NEL;
  u16*   VT   = Kb + NEL;
  float* numb = (float*)(VT + NEL);
  float* denb = numb + 4*NEL;
  float* partial = numb;

  prep_kernel<<<160, 256, 0, stream>>>(eab, eba, partial, Wq, Wk, Wv, Wo, W1, W2, WT);
  ln_qkv_kernel<<<512, 512, 0, stream>>>(xa, xb, ga, ba, WT, bq, bk, bv,
                                         partial, deg, Qb, Kb, VT);
  attn_kernel<<<dim3(32,4,8), 256, 0, stream>>>(Qb, Kb, VT, numb, denb);
  tail_kernel<<<512, 512, 0, stream>>>(numb, denb, WT, bo, deg, xa, xb,
                                       gfn, bfn, gf, bf, b1, b2, out);
}

// Round 11
// 174.735 us; speedup vs baseline: 1.0560x; 1.0113x over previous
//
#include <hip/hip_runtime.h>

typedef unsigned short u16;
typedef unsigned int   u32;
typedef __attribute__((ext_vector_type(8))) short bf16x8;   // 8 bf16 (4 VGPRs)
typedef __attribute__((ext_vector_type(4))) float f32x4;    // 16x16 MFMA acc
typedef __attribute__((ext_vector_type(16))) float f32x16;  // 32x32 MFMA acc
typedef __attribute__((ext_vector_type(4))) u32 u32x4;

#define NEL (8192*128)

// async global->LDS, 16B per lane, LDS dest = wave-uniform base + lane*16
#define ASYNC16(ldsptr, gptr) __builtin_amdgcn_global_load_lds( \
    (const __attribute__((address_space(1))) u32*)(gptr), \
    (__attribute__((address_space(3))) u32*)(ldsptr), 16, 0, 0)

__device__ __forceinline__ u16 f2bf(float f){
  u32 u = __builtin_bit_cast(u32, f);
  u = (u + 0x7FFFu + ((u >> 16) & 1u)) >> 16;  // RNE
  return (u16)u;
}
__device__ __forceinline__ u32 pk2(float a, float b){  // lo=bf16(a), hi=bf16(b)
  u32 r;
  asm("v_cvt_pk_bf16_f32 %0, %1, %2" : "=v"(r) : "v"(a), "v"(b));
  return r;
}

// ---------------- prep (unchanged from R9) ----------------
__global__ __launch_bounds__(256) void prep_kernel(
    const int* __restrict__ eab, const int* __restrict__ eba, float* __restrict__ partial,
    const float* __restrict__ Wq, const float* __restrict__ Wk, const float* __restrict__ Wv,
    const float* __restrict__ Wo, const float* __restrict__ W1, const float* __restrict__ W2,
    u16* __restrict__ WT)
{
  __shared__ u32 hist[8192];
  __shared__ float tile[32][33];
  const int b = blockIdx.x, t = threadIdx.x;
  if (b < 64){
    #pragma unroll
    for (int i=0;i<32;i++) hist[t + i*256] = 0u;
    __syncthreads();
    const int e0 = b*1024;
    #pragma unroll
    for (int i=0;i<4;i++){
      int e = e0 + t + i*256;
      atomicAdd(&hist[eab[e]],              1u);
      atomicAdd(&hist[4096 + eab[65536+e]], 1u);
      atomicAdd(&hist[4096 + eba[e]],       1u);
      atomicAdd(&hist[eba[65536+e]],        1u);
    }
    __syncthreads();
    #pragma unroll
    for (int i=0;i<32;i++){
      int bin = t + i*256;
      partial[b*8192 + bin] = (float)hist[bin];
    }
  } else {
    int id = b - 64;
    int w = id >> 4, tt = id & 15, tr = tt >> 2, tc = tt & 3;
    const float* W = (w==0)?Wq:(w==1)?Wk:(w==2)?Wv:(w==3)?Wo:(w==4)?W1:W2;
    int r = t >> 3, c4 = (t&7)*4;
    float4 v = *(const float4*)(W + (tr*32 + r)*128 + tc*32 + c4);
    tile[r][c4]=v.x; tile[r][c4+1]=v.y; tile[r][c4+2]=v.z; tile[r][c4+3]=v.w;
    __syncthreads();
    int n = t >> 3, k4 = (t&7)*4;
    u32 lo = pk2(tile[k4+0][n], tile[k4+1][n]);
    u32 hi = pk2(tile[k4+2][n], tile[k4+3][n]);
    *(uint2*)(WT + w*16384 + (tc*32+n)*128 + tr*32 + k4) = make_uint2(lo, hi);
  }
}

// ---------------- ln_qkv (unchanged from R9) ----------------
__global__ __launch_bounds__(512) void ln_qkv_kernel(
    const float* __restrict__ xa, const float* __restrict__ xb,
    const float* __restrict__ g, const float* __restrict__ bvec,
    const u16* __restrict__ WT,
    const float* __restrict__ bq, const float* __restrict__ bk, const float* __restrict__ bv,
    const float* __restrict__ partial, float* __restrict__ deg,
    u16* __restrict__ Qb, u16* __restrict__ Kb, u16* __restrict__ VT)
{
  __shared__ float xs[16][132];
  __shared__ __align__(16) u16 abf[16][128];
  __shared__ __align__(16) u16 vtb[128][24];
  const int t = threadIdx.x, lane = t&63, wave = t>>6;
  const int lq = lane&15, lg = lane>>4;
  const int row0 = blockIdx.x*16;
  const float* x = (row0 < 4096) ? (xa + row0*128) : (xb + (row0-4096)*128);
  if (t < 16){
    int bin = blockIdx.x*16 + t;
    float s = 0.f;
    #pragma unroll
    for (int j=0;j<64;j++) s += partial[j*8192 + bin];
    deg[bin] = s;
  }
  {
    int r = t>>5, c4 = (t&31)*4;
    float4 v = *(const float4*)(x + r*128 + c4);
    xs[r][c4]=v.x; xs[r][c4+1]=v.y; xs[r][c4+2]=v.z; xs[r][c4+3]=v.w;
  }
  __syncthreads();
  if (t < 256){
    int r = t>>4, c0 = t&15;
    float s=0.f, s2=0.f;
    #pragma unroll
    for (int j=0;j<8;j++){ float v = xs[r][c0+j*16]; s+=v; s2+=v*v; }
    #pragma unroll
    for (int m=1;m<16;m<<=1){ s += __shfl_xor(s,m); s2 += __shfl_xor(s2,m); }
    float mean = s*0.0078125f;
    float var  = s2*0.0078125f - mean*mean;
    float rstd = rsqrtf(var + 1e-5f);
    #pragma unroll
    for (int j=0;j<8;j++){
      int c = c0 + j*16;
      float h = (xs[r][c]-mean)*rstd*g[c] + bvec[c];
      int sj = (c>>3) ^ (r&7);
      abf[r][sj*8 + (c&7)] = f2bf(h);
    }
  }
  __syncthreads();
  bf16x8 af[4];
  #pragma unroll
  for (int s=0;s<4;s++){
    int sj = (s*4+lg) ^ (lq&7);
    af[s] = *(const bf16x8*)&abf[lq][sj*8];
  }
  const int cb = wave*16;
  const float QSC = 0.17677669529663687f * 1.4426950408889634f; // 1/sqrt(32)*log2e
  #pragma unroll
  for (int m=0;m<3;m++){
    const u16* Wg = WT + m*16384;
    bf16x8 bfr[4];
    #pragma unroll
    for (int s=0;s<4;s++)
      bfr[s] = *(const bf16x8*)(Wg + (cb+lq)*128 + s*32 + lg*8);
    f32x4 acc = {0,0,0,0};
    #pragma unroll
    for (int s=0;s<4;s++)
      acc = __builtin_amdgcn_mfma_f32_16x16x32_bf16(af[s], bfr[s], acc, 0,0,0);
    int col = cb + lq;
    if (m==0){
      float bb = bq[col];
      #pragma unroll
      for (int r=0;r<4;r++)
        Qb[(row0+4*lg+r)*128 + col] = f2bf((acc[r]+bb)*QSC);
    } else if (m==1){
      float bb = bk[col];
      #pragma unroll
      for (int r=0;r<4;r++)
        Kb[(row0+4*lg+r)*128 + col] = f2bf(acc[r]+bb);
    } else {
      float bb = bv[col];
      #pragma unroll
      for (int r=0;r<4;r++)
        vtb[col][4*lg+r] = f2bf(acc[r]+bb);
    }
  }
  __syncthreads();
  if (t < 256){
    int c = t>>1, half = t&1;
    bf16x8 v = *(const bf16x8*)&vtb[c][half*8];
    *(bf16x8*)(VT + c*8192 + row0 + half*8) = v;
  }
}

// ---------------- flash attention: 32x32 MFMA, in-register P via permlane32_swap ----------------
// grid (32, 4 heads, 8 = dir*4+split); block 256 = 4 waves x 32 q; KBLK=128, 8 tiles/split.
// S^T = K.Q^T in 32x32x16 (C: col=q=lane&31, row=key=(reg&3)+8(reg>>2)+4hi, verified layout).
// P -> PV B-frag entirely in-register: cvt_pk pairs + v_permlane32_swap (lane<->lane+32).
// K LDS: [key][4 chunks] chunk^((key>>1)&3); V^T LDS: [d][16 chunks] chunk^(d&7) — both
// spread reads evenly over all 8 bank-quads (derived even; conflict-free b128).
// 2-buffer, stage-at-top / vmcnt(0)+barrier-at-bottom (one barrier per tile).
__global__ __launch_bounds__(256, 4) void attn_kernel(
    const u16* __restrict__ Qb, const u16* __restrict__ Kb,
    const u16* __restrict__ VT, float* __restrict__ numb, float* __restrict__ denb)
{
  __shared__ __align__(16) u16 Klds[2][4096];   // 128 keys x 32 d (64B rows, 4 swz chunks)
  __shared__ __align__(16) u16 Vlds[2][4096];   // 32 d x 128 keys (256B rows, 16 swz chunks)
  const int t = threadIdx.x, wave = t>>6, lane = t&63;
  const int lo5 = lane & 31, hi = lane >> 5;
  const int h = blockIdx.y;
  const int dir = blockIdx.z >> 2, sp = blockIdx.z & 3;
  const int q = blockIdx.x*128 + wave*32 + lo5 + (dir ? 4096 : 0);
  const int kvb = (dir ? 0 : 4096) + sp*1024;

  // Q B-frags: element e -> d = dstep*16 + hi*8 + e
  bf16x8 qB0 = *(const bf16x8*)(Qb + q*128 + h*32 + hi*8);
  bf16x8 qB1 = *(const bf16x8*)(Qb + q*128 + h*32 + 16 + hi*8);

  f32x16 acc  = {0,0,0,0,0,0,0,0,0,0,0,0,0,0,0,0};
  f32x16 accL = {0,0,0,0,0,0,0,0,0,0,0,0,0,0,0,0};
  bf16x8 ones;
  #pragma unroll
  for (int i=0;i<8;i++) ones[i] = (short)0x3F80;

  // staging sources (pre-swizzled so linear LDS dest + swizzled read match):
  // K slot L: key=L>>2, c=L&3, src chunk = c ^ ((key>>1)&3); slot t+256 = +64 keys
  // V slot L: d=L>>4, c=L&15, src chunk = c ^ (d&7); slot t+256 = +16 d rows
  const u16* gk = Kb + (kvb + (t>>2))*128 + h*32 + (((t&3) ^ ((t>>3)&3))<<3);
  const u16* gv = VT + (h*32 + (t>>4))*8192 + kvb + (((t&15) ^ ((t>>4)&7))<<3);

  // prologue: tile 0 into buf 0
  ASYNC16(&Klds[0][t*8],      gk);
  ASYNC16(&Klds[0][t*8+2048], gk + 8192);     // +64 keys
  ASYNC16(&Vlds[0][t*8],      gv);
  ASYNC16(&Vlds[0][t*8+2048], gv + 131072);   // +16 d rows
  asm volatile("s_waitcnt vmcnt(0)" ::: "memory");
  __builtin_amdgcn_s_barrier();

  for (int kt=0; kt<8; ++kt){
    const int cur = kt & 1;
    if (kt < 7){                               // stage next tile into other buf
      const u16* nk = gk + (kt+1)*16384;       // +128 keys
      const u16* nv = gv + (kt+1)*128;
      ASYNC16(&Klds[cur^1][t*8],      nk);
      ASYNC16(&Klds[cur^1][t*8+2048], nk + 8192);
      ASYNC16(&Vlds[cur^1][t*8],      nv);
      ASYNC16(&Vlds[cur^1][t*8+2048], nv + 131072);
    }
    const u16* KL = Klds[cur];
    const u16* VL = Vlds[cur];
    const int dsw = lo5 & 7;
    #pragma unroll
    for (int k4=0; k4<4; ++k4){
      // QK^T: A = K rows (key = k4*32 + lo5), chunks (dstep*2+hi) ^ ((key>>1)&3)
      const int key = k4*32 + lo5;
      const int ksw = (key>>1)&3;
      bf16x8 kA0 = *(const bf16x8*)(KL + key*32 + ((hi     ^ ksw)<<3));
      bf16x8 kA1 = *(const bf16x8*)(KL + key*32 + (((2+hi) ^ ksw)<<3));
      f32x16 st = __builtin_amdgcn_mfma_f32_32x32x16_bf16(kA0, qB0,
                  (f32x16){0,0,0,0,0,0,0,0,0,0,0,0,0,0,0,0}, 0,0,0);
      st = __builtin_amdgcn_mfma_f32_32x32x16_bf16(kA1, qB1, st, 0,0,0);
      // exp2 (Q pre-scaled by 1/sqrt(D)*log2e, m==0 softmax)
      float p[16];
      #pragma unroll
      for (int r=0;r<16;r++) p[r] = __builtin_amdgcn_exp2f(st[r]);
      // pack + permlane32_swap -> PV B-frags (keys k-local 0..15 and 16..31)
      u32 a0 = pk2(p[0],p[1]),  b0 = pk2(p[4],p[5]);
      u32 c0 = pk2(p[2],p[3]),  d0 = pk2(p[6],p[7]);
      asm("v_permlane32_swap_b32 %0, %1" : "+v"(b0), "+v"(a0));
      asm("v_permlane32_swap_b32 %0, %1" : "+v"(d0), "+v"(c0));
      u32x4 u0 = {a0, c0, b0, d0};
      bf16x8 pf0 = __builtin_bit_cast(bf16x8, u0);
      u32 a1 = pk2(p[8],p[9]),   b1 = pk2(p[12],p[13]);
      u32 c1 = pk2(p[10],p[11]), d1 = pk2(p[14],p[15]);
      asm("v_permlane32_swap_b32 %0, %1" : "+v"(b1), "+v"(a1));
      asm("v_permlane32_swap_b32 %0, %1" : "+v"(d1), "+v"(c1));
      u32x4 u1 = {a1, c1, b1, d1};
      bf16x8 pf1 = __builtin_bit_cast(bf16x8, u1);
      // PV: A = V^T rows (d = lo5), chunks (s*2+hi) ^ (d&7), s = k4*2, k4*2+1
      bf16x8 vA0 = *(const bf16x8*)(VL + lo5*128 + (((k4*4   + hi) ^ dsw)<<3));
      bf16x8 vA1 = *(const bf16x8*)(VL + lo5*128 + (((k4*4+2 + hi) ^ dsw)<<3));
      __builtin_amdgcn_s_setprio(1);
      acc  = __builtin_amdgcn_mfma_f32_32x32x16_bf16(vA0,  pf0, acc,  0,0,0);
      accL = __builtin_amdgcn_mfma_f32_32x32x16_bf16(ones, pf0, accL, 0,0,0);
      acc  = __builtin_amdgcn_mfma_f32_32x32x16_bf16(vA1,  pf1, acc,  0,0,0);
      accL = __builtin_amdgcn_mfma_f32_32x32x16_bf16(ones, pf1, accL, 0,0,0);
      __builtin_amdgcn_s_setprio(0);
    }
    if (kt < 7){
      asm volatile("s_waitcnt vmcnt(0)" ::: "memory");
      __builtin_amdgcn_s_barrier();
    }
  }
  // store raw partials: C row d = (reg&3) + 8*(reg>>2) + 4*hi, col q = lo5
  float* o = numb + sp*NEL + q*128 + h*32;
  #pragma unroll
  for (int rg=0; rg<4; ++rg){
    int d0 = 8*rg + 4*hi;
    *(float4*)(o + d0) = make_float4(acc[rg*4+0], acc[rg*4+1], acc[rg*4+2], acc[rg*4+3]);
  }
  if (hi == 0) denb[sp*32768 + q*4 + h] = accL[0];
}

// ---------------- MFMA tail (unchanged from R9) ----------------
__global__ __launch_bounds__(512) void tail_kernel(
    const float* __restrict__ numb, const float* __restrict__ denb,
    const u16* __restrict__ WT,
    const float* __restrict__ bo, const float* __restrict__ deg,
    const float* __restrict__ xa, const float* __restrict__ xb,
    const float* __restrict__ gf1, const float* __restrict__ bf1,
    const float* __restrict__ gf2, const float* __restrict__ bf2,
    const float* __restrict__ b1, const float* __restrict__ b2,
    float* __restrict__ out)
{
  __shared__ __align__(16) u16 abf[16][128];
  __shared__ float rs[16][132];
  const int t = threadIdx.x, lane = t&63, wave = t>>6;
  const int lq = lane&15, lg = lane>>4;
  const int row0 = blockIdx.x*16;
  const int cb = wave*16;

  {
    int r = t>>5, c0 = (t&31)*4, hh = c0>>5;
    const float* np = numb + (row0+r)*128 + c0;
    float4 s0 = *(const float4*)(np);
    float4 s1 = *(const float4*)(np + NEL);
    float4 s2 = *(const float4*)(np + 2*NEL);
    float4 s3 = *(const float4*)(np + 3*NEL);
    int di = (row0+r)*4 + hh;
    float den = denb[di] + denb[32768+di] + denb[65536+di] + denb[98304+di];
    float inv = 1.0f/den;
    float a0 = (s0.x+s1.x+s2.x+s3.x)*inv;
    float a1 = (s0.y+s1.y+s2.y+s3.y)*inv;
    float a2 = (s0.z+s1.z+s2.z+s3.z)*inv;
    float a3 = (s0.w+s1.w+s2.w+s3.w)*inv;
    int sj = (c0>>3) ^ (r&7);
    *(uint2*)&abf[r][sj*8 + (c0&7)] = make_uint2(pk2(a0,a1), pk2(a2,a3));
  }
  __syncthreads();

  bf16x8 af[4];
  #pragma unroll
  for (int s=0;s<4;s++){ int sj = (s*4+lg) ^ (lq&7); af[s] = *(const bf16x8*)&abf[lq][sj*8]; }

  f32x4 acc = {0,0,0,0};
  {
    const u16* Wg = WT + 3*16384;
    bf16x8 bfr[4];
    #pragma unroll
    for (int s=0;s<4;s++) bfr[s] = *(const bf16x8*)(Wg + (cb+lq)*128 + s*32 + lg*8);
    #pragma unroll
    for (int s=0;s<4;s++) acc = __builtin_amdgcn_mfma_f32_16x16x32_bf16(af[s], bfr[s], acc, 0,0,0);
  }
  const float* xres = (row0<4096)? (xa + row0*128) : (xb + (row0-4096)*128);
  const int col = cb + lq;
  float rv[4];
  {
    float bb = bo[col];
    #pragma unroll
    for (int r=0;r<4;r++){
      int lr = 4*lg + r;
      rv[r] = acc[r] + bb + deg[row0+lr] + xres[lr*128 + col];
      rs[lr][col] = rv[r];
    }
  }
  __syncthreads();
  if (t < 256){
    int r = t>>4, c0 = t&15;
    float s=0.f, s2=0.f;
    #pragma unroll
    for (int j=0;j<8;j++){ float v = rs[r][c0+j*16]; s+=v; s2+=v*v; }
    #pragma unroll
    for (int m=1;m<16;m<<=1){ s += __shfl_xor(s,m); s2 += __shfl_xor(s2,m); }
    float mean = s*0.0078125f;
    float var  = s2*0.0078125f - mean*mean;
    float rstd = rsqrtf(var + 1e-5f);
    float h8[8];
    #pragma unroll
    for (int j=0;j<8;j++){ int c=c0+j*16; h8[j] = (rs[r][c]-mean)*rstd*gf1[c] + bf1[c]; }
    s=0.f; s2=0.f;
    #pragma unroll
    for (int j=0;j<8;j++){ s+=h8[j]; s2+=h8[j]*h8[j]; }
    #pragma unroll
    for (int m=1;m<16;m<<=1){ s += __shfl_xor(s,m); s2 += __shfl_xor(s2,m); }
    float mean2 = s*0.0078125f;
    float var2  = s2*0.0078125f - mean2*mean2;
    float rstd2 = rsqrtf(var2 + 1e-5f);
    #pragma unroll
    for (int j=0;j<8;j++){
      int c = c0 + j*16;
      float h = (h8[j]-mean2)*rstd2*gf2[c] + bf2[c];
      int sj = (c>>3) ^ (r&7);
      abf[r][sj*8 + (c&7)] = f2bf(h);
    }
  }
  __syncthreads();
  #pragma unroll
  for (int s=0;s<4;s++){ int sj = (s*4+lg) ^ (lq&7); af[s] = *(const bf16x8*)&abf[lq][sj*8]; }
  acc = (f32x4){0,0,0,0};
  {
    const u16* Wg = WT + 4*16384;
    bf16x8 bfr[4];
    #pragma unroll
    for (int s=0;s<4;s++) bfr[s] = *(const bf16x8*)(Wg + (cb+lq)*128 + s*32 + lg*8);
    #pragma unroll
    for (int s=0;s<4;s++) acc = __builtin_amdgcn_mfma_f32_16x16x32_bf16(af[s], bfr[s], acc, 0,0,0);
  }
  float gvv[4];
  {
    float bb = b1[col];
    #pragma unroll
    for (int r=0;r<4;r++){
      float v = acc[r] + bb;
      gvv[r] = 0.5f*v*(1.f + erff(v*0.70710678118654752f));
    }
  }
  __syncthreads();
  #pragma unroll
  for (int r=0;r<4;r++){
    int lr = 4*lg + r;
    int sj = (col>>3) ^ (lr&7);
    abf[lr][sj*8 + (col&7)] = f2bf(gvv[r]);
  }
  __syncthreads();
  #pragma unroll
  for (int s=0;s<4;s++){ int sj = (s*4+lg) ^ (lq&7); af[s] = *(const bf16x8*)&abf[lq][sj*8]; }
  acc = (f32x4){0,0,0,0};
  {
    const u16* Wg = WT + 5*16384;
    bf16x8 bfr[4];
    #pragma unroll
    for (int s=0;s<4;s++) bfr[s] = *(const bf16x8*)(Wg + (cb+lq)*128 + s*32 + lg*8);
    #pragma unroll
    for (int s=0;s<4;s++) acc = __builtin_amdgcn_mfma_f32_16x16x32_bf16(af[s], bfr[s], acc, 0,0,0);
  }
  {
    float bb = b2[col];
    #pragma unroll
    for (int r=0;r<4;r++){
      int lr = 4*lg + r;
      out[(row0+lr)*128 + col] = acc[r] + bb + rv[r];
    }
  }
}

extern "C" void kernel_launch(void* const* d_in, const int* in_sizes, int n_in,
                              void* d_out, int out_size, void* d_ws, size_t ws_size,
                              hipStream_t stream) {
  const float* xa  = (const float*)d_in[0];
  const float* xb  = (const float*)d_in[1];
  const int*   eab = (const int*)d_in[2];
  const int*   eba = (const int*)d_in[3];
  const float* Wq  = (const float*)d_in[4];   const float* bq = (const float*)d_in[5];
  const float* Wk  = (const float*)d_in[6];   const float* bk = (const float*)d_in[7];
  const float* Wv  = (const float*)d_in[8];   const float* bv = (const float*)d_in[9];
  const float* Wo  = (const float*)d_in[10];  const float* bo = (const float*)d_in[11];
  const float* ga  = (const float*)d_in[12];  const float* ba = (const float*)d_in[13];
  const float* gfn = (const float*)d_in[14];  const float* bfn= (const float*)d_in[15];
  const float* gf  = (const float*)d_in[16];  const float* bf = (const float*)d_in[17];
  const float* W1  = (const float*)d_in[18];  const float* b1 = (const float*)d_in[19];
  const float* W2  = (const float*)d_in[20];  const float* b2 = (const float*)d_in[21];
  float* out = (float*)d_out;

  // ws: deg 32KB | WT 192KB | Qb,Kb,VT 2MB each | numb 16MB | denb 512KB  (~23MB)
  // partial[64][8192] (2MB) aliases numb: dead before attn writes numb.
  char* w = (char*)d_ws;
  float* deg  = (float*)w;
  u16*   WT   = (u16*)(w + 32768);
  u16*   Qb   = (u16*)(w + 32768 + 196608);
  u16*   Kb   = Qb + NEL;
  u16*   VT   = Kb + NEL;
  float* numb = (float*)(VT + NEL);
  float* denb = numb + 4*NEL;
  float* partial = numb;

  prep_kernel<<<160, 256, 0, stream>>>(eab, eba, partial, Wq, Wk, Wv, Wo, W1, W2, WT);
  ln_qkv_kernel<<<512, 512, 0, stream>>>(xa, xb, ga, ba, WT, bq, bk, bv,
                                         partial, deg, Qb, Kb, VT);
  attn_kernel<<<dim3(32,4,8), 256, 0, stream>>>(Qb, Kb, VT, numb, denb);
  tail_kernel<<<512, 512, 0, stream>>>(numb, denb, WT, bo, deg, xa, xb,
                                       gfn, bfn, gf, bf, b1, b2, out);
}